// Round 1
// baseline (485.257 us; speedup 1.0000x reference)
//
#include <hip/hip_runtime.h>

// BilateralRotation: out[b,c] = R1[c] @ wkv[b,c] @ R2[c]
// R = Cayley(p) = (I - A)(I + A)^{-1}, A = 0.5(p - p^T)
// B=512, C=32, H=W=64. wkv/out fp32; compute in bf16 MFMA (threshold 0.108 permits).

#define NHEADS 32
#define TILE_ELEMS 4096   // 64*64

typedef __attribute__((ext_vector_type(8))) short bf16x8;     // MFMA A/B frag (8 bf16)
typedef __attribute__((ext_vector_type(16))) float f32x16;    // MFMA C/D frag (32x32)
typedef __attribute__((ext_vector_type(4))) unsigned short us4;

static __device__ __forceinline__ unsigned short f2bf(float f) {
    union { float f; unsigned u; } v; v.f = f;
    unsigned r = v.u + 0x7fffu + ((v.u >> 16) & 1u);  // round-to-nearest-even
    return (unsigned short)(r >> 16);
}

// ---------------------------------------------------------------------------
// Kernel 1: Cayley transform. 64 blocks: blk<32 -> left head (R1 row-major),
// blk>=32 -> right head (R2 stored TRANSPOSED so main kernel B-frags are
// contiguous k-runs). Gauss-Jordan without pivoting: M = I+A has SPD
// symmetric part -> elimination stable, never singular.
// ---------------------------------------------------------------------------
__global__ __launch_bounds__(256) void cayley_kernel(
    const float* __restrict__ p_left, const float* __restrict__ p_right,
    unsigned short* __restrict__ ws_r1, unsigned short* __restrict__ ws_r2t) {
    __shared__ float M[64][65];   // stride 65: column access (m*65+j)%32=(m+j)%32 conflict-free
    __shared__ float N[64][65];
    __shared__ float fcol[64];

    const int t = threadIdx.x;
    const int side = blockIdx.x >> 5;
    const int c = blockIdx.x & 31;
    const float* p = (side ? p_right : p_left) + c * TILE_ELEMS;

    // load p into N row-major (coalesced float4)
    for (int i = 0; i < 4; ++i) {
        int f = t + 256 * i;            // float4 index 0..1023
        int r = f >> 4, c4 = f & 15;
        float4 v = ((const float4*)p)[f];
        N[r][c4 * 4 + 0] = v.x; N[r][c4 * 4 + 1] = v.y;
        N[r][c4 * 4 + 2] = v.z; N[r][c4 * 4 + 3] = v.w;
    }
    __syncthreads();

    // per-thread tile: row = lane (conflict-free column reads), 16 cols per wave
    const int row = t & 63;
    const int jb  = (t >> 6) * 16;

    // M = I + 0.5(P - P^T)   (P lives in N)
    float mrow[16];
    for (int jj = 0; jj < 16; ++jj) {
        int j = jb + jj;
        float a = 0.5f * (N[row][j] - N[j][row]);
        mrow[jj] = (row == j ? 1.0f : 0.0f) + a;
    }
    __syncthreads();
    for (int jj = 0; jj < 16; ++jj) {
        int j = jb + jj;
        M[row][j] = mrow[jj];
        N[row][j] = (row == j ? 2.0f : 0.0f) - mrow[jj];   // N = I - A
    }
    __syncthreads();

    // Gauss-Jordan: reduce M to diagonal, N -> diag(M) * (I+A)^{-1}(I-A)
    for (int k = 0; k < 64; ++k) {
        if (t < 64) {
            float piv = M[k][k];
            fcol[t] = (t == k) ? 0.0f : M[t][k] / piv;
        }
        __syncthreads();
        float f = fcol[row];
        if (f != 0.0f) {
            for (int jj = 0; jj < 16; ++jj) {
                int j = jb + jj;
                M[row][j] -= f * M[k][j];   // M[k][*] is broadcast read, never written here
                N[row][j] -= f * N[k][j];
            }
        }
        __syncthreads();
    }

    // R[row][j] = N[row][j] / M[row][row]; emit bf16
    float dinv = 1.0f / M[row][row];
    if (side == 0) {
        unsigned short* dst = ws_r1 + c * TILE_ELEMS;
        for (int jj = 0; jj < 16; ++jj) {
            int j = jb + jj;
            dst[row * 64 + j] = f2bf(N[row][j] * dinv);
        }
    } else {
        unsigned short* dst = ws_r2t + c * TILE_ELEMS;
        for (int jj = 0; jj < 16; ++jj) {
            int j = jb + jj;
            dst[j * 64 + row] = f2bf(N[row][j] * dinv);    // transposed store
        }
    }
}

// ---------------------------------------------------------------------------
// Kernel 2: one block per (b,c) tile. 4 waves, each one 32x32 quadrant.
// U = W @ R2 (A = W rows, B = R2T rows), out = R1 @ U (B = UT rows).
// LDS stride 72 shorts = 144 B: 16B-aligned rows, b128 frag reads
// conflict-free in 8-lane phases (bank group (36m + k/2)%32, m 0..7 distinct).
// ---------------------------------------------------------------------------
__global__ __launch_bounds__(256, 4) void rot_kernel(
    const float* __restrict__ wkv,
    const unsigned short* __restrict__ ws_r1,
    const unsigned short* __restrict__ ws_r2t,
    float* __restrict__ out) {
    __shared__ unsigned short Wl[64][72];
    __shared__ unsigned short R1l[64][72];
    __shared__ unsigned short R2Tl[64][72];
    __shared__ unsigned short UTl[64][72];

    const int t = threadIdx.x;
    const int c = blockIdx.x & 31;
    const float* wtile = wkv + ((size_t)blockIdx.x << 12);

    // stage wkv tile: fp32 global -> bf16 LDS (coalesced float4 reads)
    for (int i = 0; i < 4; ++i) {
        int f = t + 256 * i;            // float4 index
        int r = f >> 4, c4 = f & 15;
        float4 v = ((const float4*)wtile)[f];
        us4 o;
        o[0] = f2bf(v.x); o[1] = f2bf(v.y); o[2] = f2bf(v.z); o[3] = f2bf(v.w);
        *(us4*)&Wl[r][c4 * 4] = o;
    }
    // stage R1 and R2T (bf16 in ws, coalesced 8B reads; L2-hot across 512 blocks)
    {
        const us4* s1 = (const us4*)(ws_r1 + c * TILE_ELEMS);
        const us4* s2 = (const us4*)(ws_r2t + c * TILE_ELEMS);
        for (int i = 0; i < 4; ++i) {
            int f = t + 256 * i;        // 8B chunk index 0..1023
            int r = f >> 4, c4 = f & 15;
            *(us4*)&R1l[r][c4 * 4]  = s1[f];
            *(us4*)&R2Tl[r][c4 * 4] = s2[f];
        }
    }
    __syncthreads();

    const int lane = t & 63;
    const int wave = t >> 6;
    const int l31 = lane & 31;
    const int lhi = lane >> 5;
    const int wr = (wave & 1) * 32;
    const int wc = (wave >> 1) * 32;
    const int m = wr + l31;   // A-row for this lane
    const int n = wc + l31;   // B-col for this lane

    // stage 1: U = W @ R2
    f32x16 acc;
#pragma unroll
    for (int i = 0; i < 16; ++i) acc[i] = 0.0f;
#pragma unroll
    for (int kb = 0; kb < 4; ++kb) {
        int k0 = kb * 16 + lhi * 8;
        bf16x8 a = *(const bf16x8*)&Wl[m][k0];
        bf16x8 b = *(const bf16x8*)&R2Tl[n][k0];
        acc = __builtin_amdgcn_mfma_f32_32x32x16_bf16(a, b, acc, 0, 0, 0);
    }
    // C-layout (col=lane&31, row=(reg&3)+8*(reg>>2)+4*(lane>>5)) -> UT[col][row] bf16
#pragma unroll
    for (int g = 0; g < 4; ++g) {
        int kbase = wr + 8 * g + 4 * lhi;
        us4 v;
#pragma unroll
        for (int q = 0; q < 4; ++q) v[q] = f2bf(acc[4 * g + q]);
        *(us4*)&UTl[n][kbase] = v;    // 2-way bank conflict only (free)
    }
    __syncthreads();

    // stage 2: out = R1 @ U
    f32x16 acc2;
#pragma unroll
    for (int i = 0; i < 16; ++i) acc2[i] = 0.0f;
#pragma unroll
    for (int kb = 0; kb < 4; ++kb) {
        int k0 = kb * 16 + lhi * 8;
        bf16x8 a = *(const bf16x8*)&R1l[m][k0];
        bf16x8 b = *(const bf16x8*)&UTl[n][k0];
        acc2 = __builtin_amdgcn_mfma_f32_32x32x16_bf16(a, b, acc2, 0, 0, 0);
    }

    // write fp32 tile: per (g,q) store, lanes 0..31 = 128B row segment, lanes
    // 32..63 = 128B segment 4 rows down -> fully coalesced
    float* otile = out + ((size_t)blockIdx.x << 12);
#pragma unroll
    for (int g = 0; g < 4; ++g) {
#pragma unroll
        for (int q = 0; q < 4; ++q) {
            int rowl = 8 * g + 4 * lhi + q;
            otile[(size_t)(wr + rowl) * 64 + wc + l31] = acc2[4 * g + q];
        }
    }
}

extern "C" void kernel_launch(void* const* d_in, const int* in_sizes, int n_in,
                              void* d_out, int out_size, void* d_ws, size_t ws_size,
                              hipStream_t stream) {
    const float* wkv     = (const float*)d_in[0];
    const float* p_left  = (const float*)d_in[1];
    const float* p_right = (const float*)d_in[2];
    float* out = (float*)d_out;

    unsigned short* ws_r1  = (unsigned short*)d_ws;                 // 32*4096 bf16 = 256KB
    unsigned short* ws_r2t = ws_r1 + NHEADS * TILE_ELEMS;           // +256KB

    cayley_kernel<<<64, 256, 0, stream>>>(p_left, p_right, ws_r1, ws_r2t);

    int ntiles = in_sizes[0] / TILE_ELEMS;   // B*C = 16384
    rot_kernel<<<ntiles, 256, 0, stream>>>(wkv, ws_r1, ws_r2t, out);
}

// Round 2
// 477.095 us; speedup vs baseline: 1.0171x; 1.0171x over previous
//
#include <hip/hip_runtime.h>

// BilateralRotation: out[b,c] = R1[c] @ wkv[b,c] @ R2[c]
// R = Cayley(p) = (I - A)(I + A)^{-1}, A = 0.5(p - p^T)
// B=512, C=32, H=W=64. wkv/out fp32; compute in bf16 MFMA (abs threshold 0.108).
//
// R2: rot_kernel pipelined 8 tiles/block (R staged once, next-tile register
// prefetch overlaps MFMA); cayley register-resident GJ, 1 barrier/iter.

#define NHEADS 32
#define TILE_ELEMS 4096   // 64*64
#define TPB 8             // wkv tiles per rot block

typedef __attribute__((ext_vector_type(8))) short bf16x8;     // MFMA A/B frag
typedef __attribute__((ext_vector_type(16))) float f32x16;    // MFMA C/D (32x32)
typedef __attribute__((ext_vector_type(4))) unsigned short us4;

static __device__ __forceinline__ unsigned short f2bf(float f) {
    union { float f; unsigned u; } v; v.f = f;
    unsigned r = v.u + 0x7fffu + ((v.u >> 16) & 1u);  // round-to-nearest-even
    return (unsigned short)(r >> 16);
}

// ---------------------------------------------------------------------------
// Kernel 1: Cayley. 64 blocks (32 left -> R1 row-major, 32 right -> R2
// TRANSPOSED). Register-resident Gauss-Jordan: thread (row, sl) owns
// M[row][16sl..16sl+15] and N[...] in VGPRs. Per iter k, only row k's slices
// + column-k factors pass through double-buffered LDS -> 1 barrier/iter.
// M = I+A has SPD symmetric part -> no pivoting needed.
// ---------------------------------------------------------------------------
__global__ __launch_bounds__(256) void cayley_kernel(
    const float* __restrict__ p_left, const float* __restrict__ p_right,
    unsigned short* __restrict__ ws_r1, unsigned short* __restrict__ ws_r2t) {
    __shared__ float P[64][68];       // stride 68: float4-aligned rows
    __shared__ float frowM[2][64];
    __shared__ float frowN[2][64];
    __shared__ float fcol[2][64];
    __shared__ float dinv_l[64];

    const int t = threadIdx.x;
    const int side = blockIdx.x >> 5;
    const int c = blockIdx.x & 31;
    const float* p = (side ? p_right : p_left) + c * TILE_ELEMS;

    // load p row-major (coalesced float4)
    for (int i = 0; i < 4; ++i) {
        int f = t + 256 * i;            // float4 index 0..1023
        int r = f >> 4, c4 = f & 15;
        *(float4*)&P[r][c4 * 4] = ((const float4*)p)[f];
    }
    __syncthreads();

    const int row = t & 63;
    const int sl  = t >> 6;
    const int jb  = sl * 16;

    // M = I + A, N = I - A in registers
    float mreg[16], nreg[16];
#pragma unroll
    for (int jj = 0; jj < 16; ++jj) {
        int j = jb + jj;
        float a = 0.5f * (P[row][j] - P[j][row]);
        float e = (row == j) ? 1.0f : 0.0f;
        mreg[jj] = e + a;
        nreg[jj] = e - a;
    }

    // Gauss-Jordan to diagonal; N -> diag(M) * R
    int buf = 0;
    for (int k = 0; k < 64; ++k) {
        const int kb = k >> 4, kk = k & 15;
        if (row == k) {
#pragma unroll
            for (int jj = 0; jj < 16; ++jj) {
                frowM[buf][jb + jj] = mreg[jj];
                frowN[buf][jb + jj] = nreg[jj];
            }
        }
        if (sl == kb) fcol[buf][row] = mreg[kk];
        __syncthreads();
        // safe single barrier: double-buffered staging; iter k+2 writes to
        // parity(k) only after barrier k+1, which postdates all iter-k reads.
        float pinv = __builtin_amdgcn_rcpf(frowM[buf][k]);
        float f = fcol[buf][row] * pinv;
        if (row != k) {
#pragma unroll
            for (int jj = 0; jj < 16; ++jj) {
                mreg[jj] -= f * frowM[buf][jb + jj];
                nreg[jj] -= f * frowN[buf][jb + jj];
            }
        }
        buf ^= 1;
    }

    if (sl == (row >> 4)) dinv_l[row] = __builtin_amdgcn_rcpf(mreg[row & 15]);
    __syncthreads();
    const float dinv = dinv_l[row];

    if (side == 0) {
        unsigned short* dst = ws_r1 + c * TILE_ELEMS;
#pragma unroll
        for (int q4 = 0; q4 < 4; ++q4) {
            us4 v;
#pragma unroll
            for (int q = 0; q < 4; ++q) v[q] = f2bf(nreg[q4 * 4 + q] * dinv);
            *(us4*)&dst[row * 64 + jb + q4 * 4] = v;
        }
    } else {
        unsigned short* dst = ws_r2t + c * TILE_ELEMS;
#pragma unroll
        for (int jj = 0; jj < 16; ++jj)
            dst[(jb + jj) * 64 + row] = f2bf(nreg[jj] * dinv);  // transposed
    }
}

// ---------------------------------------------------------------------------
// Kernel 2: 2048 blocks; block = (head c, 8 consecutive b). 4 waves, each a
// 32x32 quadrant. Per tile: U = W @ R2 (B = R2T rows), out = R1 @ U (B = UT
// rows, transposed via LDS from MFMA C-layout). Pipeline: next tile's float4s
// prefetched into VGPRs right after barrier 1 -> HBM latency overlaps both
// MFMA stages. LDS stride 72 shorts (144 B): b128 frag reads conflict-free.
// ---------------------------------------------------------------------------
__global__ __launch_bounds__(256, 4) void rot_kernel(
    const float* __restrict__ wkv,
    const unsigned short* __restrict__ ws_r1,
    const unsigned short* __restrict__ ws_r2t,
    float* __restrict__ out) {
    __shared__ unsigned short R1l[64][72];
    __shared__ unsigned short R2Tl[64][72];
    __shared__ unsigned short Wl[64][72];
    __shared__ unsigned short UTl[64][72];

    const int t = threadIdx.x;
    const int c = blockIdx.x & 31;
    const int bg = blockIdx.x >> 5;
    const size_t tile0 = (size_t)(bg * TPB) * NHEADS + c;   // flat (b,c) index

    // stage R1 / R2T once (bf16, coalesced 8B, L2-hot)
    {
        const us4* s1 = (const us4*)(ws_r1 + c * TILE_ELEMS);
        const us4* s2 = (const us4*)(ws_r2t + c * TILE_ELEMS);
        for (int i = 0; i < 4; ++i) {
            int f = t + 256 * i;
            int r = f >> 4, c4 = f & 15;
            *(us4*)&R1l[r][c4 * 4]  = s1[f];
            *(us4*)&R2Tl[r][c4 * 4] = s2[f];
        }
    }

    // prefetch tile 0 into registers
    float4 pf[4];
    {
        const float4* wt = (const float4*)(wkv + tile0 * TILE_ELEMS);
#pragma unroll
        for (int i = 0; i < 4; ++i) pf[i] = wt[t + 256 * i];
    }

    const int lane = t & 63;
    const int wave = t >> 6;
    const int l31 = lane & 31;
    const int lhi = lane >> 5;
    const int wr = (wave & 1) * 32;
    const int wc = (wave >> 1) * 32;
    const int m = wr + l31;
    const int n = wc + l31;

    for (int j = 0; j < TPB; ++j) {
        // W tile: registers (fp32) -> LDS (bf16)
#pragma unroll
        for (int i = 0; i < 4; ++i) {
            int f = t + 256 * i;
            int r = f >> 4, c4 = f & 15;
            us4 o;
            o[0] = f2bf(pf[i].x); o[1] = f2bf(pf[i].y);
            o[2] = f2bf(pf[i].z); o[3] = f2bf(pf[i].w);
            *(us4*)&Wl[r][c4 * 4] = o;
        }
        __syncthreads();   // B1: W (and first-iter R) visible; UT of j-1 fully read

        // prefetch next tile (overlaps both MFMA stages below)
        if (j + 1 < TPB) {
            const float4* wn = (const float4*)(wkv + (tile0 + (size_t)(j + 1) * NHEADS) * TILE_ELEMS);
#pragma unroll
            for (int i = 0; i < 4; ++i) pf[i] = wn[t + 256 * i];
        }

        // stage 1: U = W @ R2
        f32x16 acc;
#pragma unroll
        for (int i = 0; i < 16; ++i) acc[i] = 0.0f;
#pragma unroll
        for (int kb = 0; kb < 4; ++kb) {
            int k0 = kb * 16 + lhi * 8;
            bf16x8 a = *(const bf16x8*)&Wl[m][k0];
            bf16x8 b = *(const bf16x8*)&R2Tl[n][k0];
            acc = __builtin_amdgcn_mfma_f32_32x32x16_bf16(a, b, acc, 0, 0, 0);
        }
        // C-layout (col=lane&31, row=(reg&3)+8*(reg>>2)+4*lhi) -> UT[col][row]
#pragma unroll
        for (int g = 0; g < 4; ++g) {
            int kbase = wr + 8 * g + 4 * lhi;
            us4 v;
#pragma unroll
            for (int q = 0; q < 4; ++q) v[q] = f2bf(acc[4 * g + q]);
            *(us4*)&UTl[n][kbase] = v;   // 2-way conflict only (free)
        }
        __syncthreads();   // B2: UT visible; W of this iter fully read

        // stage 2: out = R1 @ U
        f32x16 acc2;
#pragma unroll
        for (int i = 0; i < 16; ++i) acc2[i] = 0.0f;
#pragma unroll
        for (int kb = 0; kb < 4; ++kb) {
            int k0 = kb * 16 + lhi * 8;
            bf16x8 a = *(const bf16x8*)&R1l[m][k0];
            bf16x8 b = *(const bf16x8*)&UTl[n][k0];
            acc2 = __builtin_amdgcn_mfma_f32_32x32x16_bf16(a, b, acc2, 0, 0, 0);
        }

        // store fp32 tile: each store = 2 x 128B segments, fully coalesced
        float* otile = out + (tile0 + (size_t)j * NHEADS) * TILE_ELEMS;
#pragma unroll
        for (int g = 0; g < 4; ++g) {
#pragma unroll
            for (int q = 0; q < 4; ++q) {
                int rowl = 8 * g + 4 * lhi + q;
                otile[(size_t)(wr + rowl) * 64 + wc + l31] = acc2[4 * g + q];
            }
        }
    }
}

extern "C" void kernel_launch(void* const* d_in, const int* in_sizes, int n_in,
                              void* d_out, int out_size, void* d_ws, size_t ws_size,
                              hipStream_t stream) {
    const float* wkv     = (const float*)d_in[0];
    const float* p_left  = (const float*)d_in[1];
    const float* p_right = (const float*)d_in[2];
    float* out = (float*)d_out;

    unsigned short* ws_r1  = (unsigned short*)d_ws;           // 32*4096 bf16
    unsigned short* ws_r2t = ws_r1 + NHEADS * TILE_ELEMS;

    cayley_kernel<<<64, 256, 0, stream>>>(p_left, p_right, ws_r1, ws_r2t);

    int ntiles = in_sizes[0] / TILE_ELEMS;          // B*C = 16384
    rot_kernel<<<ntiles / TPB, 256, 0, stream>>>(wkv, ws_r1, ws_r2t, out);
}